// Round 1
// baseline (198.731 us; speedup 1.0000x reference)
//
#include <hip/hip_runtime.h>
#include <hip/hip_bf16.h>

// MultiHeadAttentionBlock: B=4, S=2048, D=512, H=8, DK=64, causal.
// Inputs/outputs fp32; internal compute bf16 MFMA (2%-rel threshold allows it).
// Pipeline: fp32->bf16 convert -> qkv_gemm (fused 3x, Q pre-scaled, V stored
// transposed [B,H,DK,S]) -> flash attention -> oproj gemm (fp32 out).
// R11: causal q-tile PAIRING in attention. R10's grid (32 bh, 32 qt) had
//      uniform per-CU totals but decaying concurrency (4->1 blocks/CU as
//      short causal blocks finished; measured OccupancyPercent 21.6%,
//      MfmaUtil 13.6%). Now each block owns q-tiles (g, 31-g) and iterates
//      kv=0..31-g: long tile every iter, short tile while kv<=g -> exactly
//      33 tile-computations per block, zero tail. K/V staging, kf/vf
//      ds_reads and barriers are shared between the two tiles in the
//      overlap phase (32 MFMA/wave/iter vs 16). Grid (32,16)=512 blocks
//      = 2/CU uniform; x->pair map p = x<8 ? x : 23-x puts pairs (g,15-g)
//      on one CU (ids c, c+256 co-resident) -> per-CU 49 iterations, and
//      both resident blocks share (b,h) -> K/V L2 reuse.

#define BATCH  4
#define SLEN   2048
#define DMODEL 512
#define NHEAD  8
#define DHEAD  64
#define MROWS  (BATCH * SLEN)   // 8192

#define NQ ((size_t)MROWS * DMODEL)     // 4194304 per q/k/v tensor
#define NW ((size_t)DMODEL * DMODEL)    // 262144 per weight
#define NB ((size_t)DMODEL)             // 512 per bias
#define CVT_TOTAL (3 * NQ + 4 * NW + 4 * NB)   // 13633536

#define SCALE_L2E 0.180336880f // (1/8) * log2(e): softmax in log2 domain

typedef short bf16x8 __attribute__((ext_vector_type(8)));
typedef float f32x4  __attribute__((ext_vector_type(4)));

typedef unsigned int __attribute__((address_space(1))) glb_u32_t;
typedef unsigned int __attribute__((address_space(3))) lds_u32_t;

__device__ __forceinline__ void async_copy16(const unsigned short* g, unsigned short* l) {
    // 16B per lane, HW writes LDS at wave-uniform base + lane*16
    __builtin_amdgcn_global_load_lds((glb_u32_t*)g, (lds_u32_t*)l, 16, 0, 0);
}

__device__ __forceinline__ float bf2f(unsigned short u) {
    union { unsigned int i; float f; } v; v.i = ((unsigned int)u) << 16; return v.f;
}
__device__ __forceinline__ unsigned short f2bf(float f) {
    union { float f; unsigned int i; } v; v.f = f;
    unsigned int x = v.i;
    return (unsigned short)((x + 0x7fffu + ((x >> 16) & 1u)) >> 16);
}
__device__ __forceinline__ unsigned int pkbf(float a, float b) {
    union { __hip_bfloat162 h; unsigned int u; } cv;
    cv.h = __float22bfloat162_rn(float2{a, b});
    return cv.u;
}

__device__ __forceinline__ void wait0_barrier() {
    // only this wave's current-tile asyncs are outstanding here -> exact wait,
    // then barrier joins all waves (their asyncs also retired). One per iter.
    asm volatile("s_waitcnt vmcnt(0)" ::: "memory");
    __builtin_amdgcn_s_barrier();
    asm volatile("" ::: "memory");
}

// ---------------- fp32 -> bf16 conversion pre-pass ----------------
__global__ __launch_bounds__(256)
void cvt_kernel(const float* __restrict__ q, const float* __restrict__ k,
                const float* __restrict__ v,
                const float* __restrict__ wq, const float* __restrict__ wk,
                const float* __restrict__ wv, const float* __restrict__ wo,
                const float* __restrict__ bq, const float* __restrict__ bk,
                const float* __restrict__ bv, const float* __restrict__ bo,
                unsigned short* __restrict__ dst)
{
    const size_t i4 = ((size_t)blockIdx.x * 256 + threadIdx.x) * 4;
    if (i4 >= CVT_TOTAL) return;
    const float* src;
    size_t off;
    if      (i4 <     NQ)          { src = q;  off = i4; }
    else if (i4 < 2 * NQ)          { src = k;  off = i4 - NQ; }
    else if (i4 < 3 * NQ)          { src = v;  off = i4 - 2 * NQ; }
    else if (i4 < 3 * NQ + NW)     { src = wq; off = i4 - 3 * NQ; }
    else if (i4 < 3 * NQ + 2 * NW) { src = wk; off = i4 - 3 * NQ - NW; }
    else if (i4 < 3 * NQ + 3 * NW) { src = wv; off = i4 - 3 * NQ - 2 * NW; }
    else if (i4 < 3 * NQ + 4 * NW) { src = wo; off = i4 - 3 * NQ - 3 * NW; }
    else if (i4 < 3 * NQ + 4 * NW + NB)     { src = bq; off = i4 - 3 * NQ - 4 * NW; }
    else if (i4 < 3 * NQ + 4 * NW + 2 * NB) { src = bk; off = i4 - 3 * NQ - 4 * NW - NB; }
    else if (i4 < 3 * NQ + 4 * NW + 3 * NB) { src = bv; off = i4 - 3 * NQ - 4 * NW - 2 * NB; }
    else                                    { src = bo; off = i4 - 3 * NQ - 4 * NW - 3 * NB; }
    const float4 f = *(const float4*)(src + off);
    ushort4 o;
    o.x = f2bf(f.x); o.y = f2bf(f.y); o.z = f2bf(f.z); o.w = f2bf(f.w);
    *(ushort4*)(dst + i4) = o;
}

// ---------------- GEMM: C[M,512] = A[M,512] * W[512,512]^T + bias ----------------
// 128x128 tile, BK=32, 4 waves -> 64x64 each. Double-buffered LDS, pipelined,
// single barrier per K-iteration.
// Rows are 4 chunks of 16B; physical chunk = logical ^ (row&3) (conflict-free).
// mode: 0 = bf16 out scaled by SCALE_L2E (Q)   1 = bf16 out (K)
//       2 = bf16 out transposed [B,H,DK,S] (V) 3 = fp32 out (final proj)
template <typename OutT>
__device__ __forceinline__ void gemm_body(const unsigned short* __restrict__ A,
                                          const unsigned short* __restrict__ W,
                                          const unsigned short* __restrict__ bias,
                                          OutT* __restrict__ C, int mode)
{
    __shared__ __align__(16) unsigned short As[2][128 * 32];
    __shared__ __align__(16) unsigned short Bs[2][128 * 32];

    const int tid  = threadIdx.x;
    const int wave = tid >> 6;
    const int lane = tid & 63;
    const int l15  = lane & 15;
    const int quad = lane >> 4;
    const int m0   = blockIdx.x * 128;
    const int n0   = blockIdx.y * 128;
    const int wm   = (wave & 1) * 64;
    const int wn   = (wave >> 1) * 64;
    const int srow = lane >> 2;                              // 0..15 within 16-row chunk
    const int scol = (((lane & 3) ^ (srow & 3)) * 8);        // swizzled k offset (bf16)
    const int rsw  = (quad ^ (l15 & 3)) * 8;                 // swizzled read offset

    auto stage = [&](int k0, int buf) {
        async_copy16(A + (size_t)(m0 + wave * 16 + srow) * DMODEL + k0 + scol, As[buf] + wave * 512);
        async_copy16(A + (size_t)(m0 + (wave + 4) * 16 + srow) * DMODEL + k0 + scol, As[buf] + (wave + 4) * 512);
        async_copy16(W + (size_t)(n0 + wave * 16 + srow) * DMODEL + k0 + scol, Bs[buf] + wave * 512);
        async_copy16(W + (size_t)(n0 + (wave + 4) * 16 + srow) * DMODEL + k0 + scol, Bs[buf] + (wave + 4) * 512);
    };

    f32x4 acc[4][4] = {};
    stage(0, 0);

    #pragma unroll 1
    for (int kt = 0; kt < 16; kt++) {
        const int cur = kt & 1;
        wait0_barrier();
        if (kt < 15) stage((kt + 1) * 32, cur ^ 1);

        bf16x8 af[4], bfr[4];
        #pragma unroll
        for (int i = 0; i < 4; i++)
            af[i] = *(const bf16x8*)(As[cur] + (wm + i * 16 + l15) * 32 + rsw);
        #pragma unroll
        for (int j = 0; j < 4; j++)
            bfr[j] = *(const bf16x8*)(Bs[cur] + (wn + j * 16 + l15) * 32 + rsw);
        #pragma unroll
        for (int i = 0; i < 4; i++)
            #pragma unroll
            for (int j = 0; j < 4; j++)
                acc[i][j] = __builtin_amdgcn_mfma_f32_16x16x32_bf16(af[i], bfr[j], acc[i][j], 0, 0, 0);
        // ds_reads retired via MFMA-forced lgkm waits before the next barrier
    }

    // epilogue: C/D layout col = lane&15, row = quad*4 + reg
    if (mode == 2) {
        // V^T store: col -> (h,dk), row -> (b,s); 4 consecutive s per reg quad
        #pragma unroll
        for (int j = 0; j < 4; j++) {
            const int col = n0 + wn + j * 16 + l15;
            const float bv = bf2f(bias[col]);
            const int hh = col >> 6, dk = col & 63;
            #pragma unroll
            for (int i = 0; i < 4; i++) {
                const int row = m0 + wm + i * 16 + quad * 4;
                const int bb = row >> 11, s = row & 2047;
                uint2 o2;
                o2.x = pkbf(acc[i][j][0] + bv, acc[i][j][1] + bv);
                o2.y = pkbf(acc[i][j][2] + bv, acc[i][j][3] + bv);
                *(uint2*)((unsigned short*)C + ((size_t)((bb * NHEAD + hh) * DHEAD + dk)) * SLEN + s) = o2;
            }
        }
    } else {
        const float oscale = (mode == 0) ? SCALE_L2E : 1.0f;
        #pragma unroll
        for (int j = 0; j < 4; j++) {
            const int col = n0 + wn + j * 16 + l15;
            const float bv = bf2f(bias[col]);
            #pragma unroll
            for (int i = 0; i < 4; i++) {
                const int row = m0 + wm + i * 16 + quad * 4;
                #pragma unroll
                for (int r = 0; r < 4; r++) {
                    const float val = (acc[i][j][r] + bv) * oscale;
                    if constexpr (sizeof(OutT) == 4)
                        C[(size_t)(row + r) * DMODEL + col] = val;
                    else
                        C[(size_t)(row + r) * DMODEL + col] = f2bf(val);
                }
            }
        }
    }
}

__global__ __launch_bounds__(256, 3)
void qkv_gemm_kernel(const unsigned short* __restrict__ qin,
                     const unsigned short* __restrict__ kin,
                     const unsigned short* __restrict__ vin,
                     const unsigned short* __restrict__ wq,
                     const unsigned short* __restrict__ bq,
                     const unsigned short* __restrict__ wk,
                     const unsigned short* __restrict__ bk,
                     const unsigned short* __restrict__ wv,
                     const unsigned short* __restrict__ bv,
                     unsigned short* __restrict__ qh,
                     unsigned short* __restrict__ kh,
                     unsigned short* __restrict__ vt)
{
    const int z = blockIdx.z;
    const unsigned short* A    = (z == 0) ? qin : (z == 1) ? kin : vin;
    const unsigned short* W    = (z == 0) ? wq  : (z == 1) ? wk  : wv;
    const unsigned short* bias = (z == 0) ? bq  : (z == 1) ? bk  : bv;
    unsigned short*       C    = (z == 0) ? qh  : (z == 1) ? kh  : vt;
    gemm_body<unsigned short>(A, W, bias, C, z);
}

__global__ __launch_bounds__(256, 3)
void oproj_gemm_kernel(const unsigned short* __restrict__ ctx,
                       const unsigned short* __restrict__ wo,
                       const unsigned short* __restrict__ bo,
                       float* __restrict__ out)
{
    gemm_body<float>(ctx, wo, bo, out, 3);
}

// ---------------- Flash attention (causal), S^T = K Q^T, fixed-ref softmax ----------------
// R11 paired blocks: each block owns q-tiles (qa=g, qb=31-g) of one (b,h);
// 4 waves x 16 q-rows per tile. Loop kv-tiles 0..31-g: qb computed every
// iteration, qa while kv<=g -> exactly 33 tile-computations per block.
// K/V staged once per iteration into XOR-chunk-swizzled double buffers and
// SHARED by both q-tiles (kf/vf ds_reads reused). One barrier per iter.
// Q pre-scaled by (1/8)log2e; fixed-reference softmax p = exp2(s).
// grid = (bh, x=0..15): p = x<8 ? x : 23-x gives pairs (g,15-g) on one CU
// (ids c, c+256 co-resident) -> per-CU iterations = 49 exactly, and both
// resident blocks share (b,h) -> K/V L2 reuse.
// LDS = 16K (Ks) + 16K (Vs) + 16K (Ps, 2 tiles) = 49152 B -> 3 blocks/CU cap.
__global__ __launch_bounds__(256, 2)
void attn_kernel(const unsigned short* __restrict__ qh,
                 const unsigned short* __restrict__ kh,
                 const unsigned short* __restrict__ vt,   // [B,H,DK,S]
                 unsigned short* __restrict__ ctx)
{
    __shared__ __align__(16) unsigned short Ks[2][64 * 64];       // [kv][dk], chunk-swizzled
    __shared__ __align__(16) unsigned short Vs[2][64 * 64];       // [dk][kv], chunk-swizzled
    __shared__ __align__(16) unsigned short Ps[4 * 2 * 16 * 64];  // per-wave, per-tile [q][kv]

    const int tid  = threadIdx.x;
    const int wave = tid >> 6;
    const int lane = tid & 63;
    const int l15  = lane & 15;
    const int quad = lane >> 4;

    const int bh = blockIdx.x;        // head-major: same head -> same XCD (bh % 8)
    const int x  = blockIdx.y;        // 0..15
    const int g  = (x < 8) ? x : 23 - x;   // CU gets classes {g, 15-g}
    const int qta = g;                // short q-tile: kv tiles 0..g
    const int qtb = 31 - g;           // long  q-tile: kv tiles 0..31-g
    const int b  = bh >> 3;
    const int h  = bh & 7;

    const size_t base = (size_t)b * SLEN * DMODEL + (size_t)h * DHEAD;
    const unsigned short* Q  = qh + base;
    const unsigned short* K  = kh + base;
    const unsigned short* VT = vt + (size_t)bh * DHEAD * SLEN;

    // swizzled staging offsets (8 chunks of 16B per 128B row, chunk ^= row&7)
    const int krow_l = lane >> 3;
    const int kcol_l = ((lane & 7) ^ (krow_l & 7)) * 8;

    const int qrow_a = qta * 64 + wave * 16 + l15;
    const int qrow_b = qtb * 64 + wave * 16 + l15;
    const bf16x8 qa0 = *(const bf16x8*)(Q + (size_t)qrow_a * DMODEL + quad * 8);
    const bf16x8 qa1 = *(const bf16x8*)(Q + (size_t)qrow_a * DMODEL + 32 + quad * 8);
    const bf16x8 qb0 = *(const bf16x8*)(Q + (size_t)qrow_b * DMODEL + quad * 8);
    const bf16x8 qb1 = *(const bf16x8*)(Q + (size_t)qrow_b * DMODEL + 32 + quad * 8);

    f32x4 oacc_a[4] = {};   // O^T tiles (unnormalized): col=q(l15), row=d(quad*4+r)
    f32x4 oacc_b[4] = {};
    float lsum_a = 0.0f, lsum_b = 0.0f;

    unsigned short* Pa = Ps + (wave * 2 + 0) * (16 * 64);
    unsigned short* Pb = Ps + (wave * 2 + 1) * (16 * 64);

    auto stageKV = [&](int kt, int buf) {
        async_copy16(K + (size_t)(kt * 64 + wave * 8 + krow_l) * DMODEL + kcol_l,
                     Ks[buf] + wave * 512);
        async_copy16(K + (size_t)(kt * 64 + (wave + 4) * 8 + krow_l) * DMODEL + kcol_l,
                     Ks[buf] + (wave + 4) * 512);
        async_copy16(VT + (size_t)(wave * 8 + krow_l) * SLEN + kt * 64 + kcol_l,
                     Vs[buf] + wave * 512);
        async_copy16(VT + (size_t)((wave + 4) * 8 + krow_l) * SLEN + kt * 64 + kcol_l,
                     Vs[buf] + (wave + 4) * 512);
    };

    // p = exp2(s); accumulate per-lane l; pack P^T (C-layout [kv][q]) ->
    // Ps[q][kv] with XOR chunk swizzle
    auto softmax_pack = [&](f32x4* sacc, unsigned short* Pw, float& lsum) {
        #pragma unroll
        for (int j = 0; j < 4; j++) {
            const float p0 = exp2f(sacc[j][0]);
            const float p1 = exp2f(sacc[j][1]);
            const float p2v = exp2f(sacc[j][2]);
            const float p3 = exp2f(sacc[j][3]);
            lsum += (p0 + p1) + (p2v + p3);
            uint2 pw;
            pw.x = pkbf(p0, p1);
            pw.y = pkbf(p2v, p3);
            const int chunk = (j * 2 + (quad >> 1)) ^ (l15 & 7);
            *(uint2*)(Pw + l15 * 64 + chunk * 8 + (quad & 1) * 4) = pw;
        }
    };

    auto diag_mask = [&](f32x4* sacc, int kt, int qrow) {
        #pragma unroll
        for (int j = 0; j < 4; j++)
            #pragma unroll
            for (int r = 0; r < 4; r++) {
                const int kv = kt * 64 + j * 16 + quad * 4 + r;
                if (kv > qrow) sacc[j][r] = -1e30f;   // exp2 -> exactly 0
            }
    };

    const int nkt = 32 - g;   // kv tiles for the long tile (qtb)
    stageKV(0, 0);

    #pragma unroll 1
    for (int kt = 0; kt < nkt; kt++) {
        const int cur = kt & 1;
        wait0_barrier();
        if (kt + 1 < nkt) stageKV(kt + 1, cur ^ 1);

        if (kt <= g) {
            // ---- both tiles active: share kf/vf LDS reads ----
            f32x4 sa[4] = {}, sb[4] = {};
            #pragma unroll
            for (int kk = 0; kk < 2; kk++) {
                const bf16x8 qfa = kk ? qa1 : qa0;
                const bf16x8 qfb = kk ? qb1 : qb0;
                #pragma unroll
                for (int j = 0; j < 4; j++) {
                    bf16x8 kf = *(const bf16x8*)(Ks[cur] + (j * 16 + l15) * 64
                                                    + (((kk * 4 + quad) ^ (l15 & 7)) * 8));
                    sb[j] = __builtin_amdgcn_mfma_f32_16x16x32_bf16(kf, qfb, sb[j], 0, 0, 0);
                    sa[j] = __builtin_amdgcn_mfma_f32_16x16x32_bf16(kf, qfa, sa[j], 0, 0, 0);
                }
            }
            if (kt == qta) diag_mask(sa, kt, qrow_a);   // qa diagonal (kt==g)
            softmax_pack(sa, Pa, lsum_a);
            softmax_pack(sb, Pb, lsum_b);
            asm volatile("s_waitcnt lgkmcnt(0)" ::: "memory");  // same-wave P round-trip

            #pragma unroll
            for (int kk = 0; kk < 2; kk++) {
                bf16x8 pfa = *(const bf16x8*)(Pa + l15 * 64 + (((kk * 4 + quad) ^ (l15 & 7)) * 8));
                bf16x8 pfb = *(const bf16x8*)(Pb + l15 * 64 + (((kk * 4 + quad) ^ (l15 & 7)) * 8));
                #pragma unroll
                for (int jd = 0; jd < 4; jd++) {
                    bf16x8 vf = *(const bf16x8*)(Vs[cur] + (jd * 16 + l15) * 64
                                                    + (((kk * 4 + quad) ^ (l15 & 7)) * 8));
                    oacc_a[jd] = __builtin_amdgcn_mfma_f32_16x16x32_bf16(vf, pfa, oacc_a[jd], 0, 0, 0);
                    oacc_b[jd] = __builtin_amdgcn_mfma_f32_16x16x32_bf16(vf, pfb, oacc_b[jd], 0, 0, 0);
                }
            }
        } else {
            // ---- long tile only ----
            f32x4 sb[4] = {};
            #pragma unroll
            for (int kk = 0; kk < 2; kk++) {
                const bf16x8 qfb = kk ? qb1 : qb0;
                #pragma unroll
                for (int j = 0; j < 4; j++) {
                    bf16x8 kf = *(const bf16x8*)(Ks[cur] + (j * 16 + l15) * 64
                                                    + (((kk * 4 + quad) ^ (l15 & 7)) * 8));
                    sb[j] = __builtin_amdgcn_mfma_f32_16x16x32_bf16(kf, qfb, sb[j], 0, 0, 0);
                }
            }
            if (kt == qtb) diag_mask(sb, kt, qrow_b);   // qb diagonal (last iter)
            softmax_pack(sb, Pb, lsum_b);
            asm volatile("s_waitcnt lgkmcnt(0)" ::: "memory");

            #pragma unroll
            for (int kk = 0; kk < 2; kk++) {
                bf16x8 pfb = *(const bf16x8*)(Pb + l15 * 64 + (((kk * 4 + quad) ^ (l15 & 7)) * 8));
                #pragma unroll
                for (int jd = 0; jd < 4; jd++) {
                    bf16x8 vf = *(const bf16x8*)(Vs[cur] + (jd * 16 + l15) * 64
                                                    + (((kk * 4 + quad) ^ (l15 & 7)) * 8));
                    oacc_b[jd] = __builtin_amdgcn_mfma_f32_16x16x32_bf16(vf, pfb, oacc_b[jd], 0, 0, 0);
                }
            }
        }
    }

    // one-time l reduction across the 4 quads sharing each q row, then store:
    // O^T[d][q] -> ctx[q][d], 4 consecutive d per reg quad
    {
        float la = lsum_a;
        la += __shfl_xor(la, 16, 64);
        la += __shfl_xor(la, 32, 64);
        const float invla = 1.0f / la;
        #pragma unroll
        for (int jd = 0; jd < 4; jd++) {
            uint2 o2;
            o2.x = pkbf(oacc_a[jd][0] * invla, oacc_a[jd][1] * invla);
            o2.y = pkbf(oacc_a[jd][2] * invla, oacc_a[jd][3] * invla);
            *(uint2*)(ctx + base + (size_t)qrow_a * DMODEL + jd * 16 + quad * 4) = o2;
        }
    }
    {
        float lb = lsum_b;
        lb += __shfl_xor(lb, 16, 64);
        lb += __shfl_xor(lb, 32, 64);
        const float invlb = 1.0f / lb;
        #pragma unroll
        for (int jd = 0; jd < 4; jd++) {
            uint2 o2;
            o2.x = pkbf(oacc_b[jd][0] * invlb, oacc_b[jd][1] * invlb);
            o2.y = pkbf(oacc_b[jd][2] * invlb, oacc_b[jd][3] * invlb);
            *(uint2*)(ctx + base + (size_t)qrow_b * DMODEL + jd * 16 + quad * 4) = o2;
        }
    }
}

extern "C" void kernel_launch(void* const* d_in, const int* in_sizes, int n_in,
                              void* d_out, int out_size, void* d_ws, size_t ws_size,
                              hipStream_t stream)
{
    const float* q   = (const float*)d_in[0];
    const float* k   = (const float*)d_in[1];
    const float* v   = (const float*)d_in[2];
    // d_in[3] = causal mask (int32) — causality implemented directly
    const float* w_q = (const float*)d_in[4];
    const float* b_q = (const float*)d_in[5];
    const float* w_k = (const float*)d_in[6];
    const float* b_k = (const float*)d_in[7];
    const float* w_v = (const float*)d_in[8];
    const float* b_v = (const float*)d_in[9];
    const float* w_o = (const float*)d_in[10];
    const float* b_o = (const float*)d_in[11];
    float* out = (float*)d_out;

    unsigned short* ws = (unsigned short*)d_ws;
    // bf16 workspace layout (elements):
    unsigned short* qb  = ws;                       // NQ
    unsigned short* kb  = ws + NQ;                  // NQ
    unsigned short* vb  = ws + 2 * NQ;              // NQ
    unsigned short* wqb = ws + 3 * NQ;              // NW
    unsigned short* wkb = wqb + NW;
    unsigned short* wvb = wkb + NW;
    unsigned short* wob = wvb + NW;
    unsigned short* bqb = wob + NW;                 // NB
    unsigned short* bkb = bqb + NB;
    unsigned short* bvb = bkb + NB;
    unsigned short* bob = bvb + NB;
    unsigned short* qh  = bob + NB;                 // NQ each below
    unsigned short* kh  = qh + NQ;
    unsigned short* vt  = kh + NQ;                  // [B,H,DK,S]
    unsigned short* ctx = vt + NQ;

    dim3 blk(256);
    hipLaunchKernelGGL(cvt_kernel, dim3((unsigned)(CVT_TOTAL / 4 / 256)), blk, 0, stream,
                       q, k, v, w_q, w_k, w_v, w_o, b_q, b_k, b_v, b_o, ws);
    hipLaunchKernelGGL(qkv_gemm_kernel, dim3(MROWS / 128, DMODEL / 128, 3), blk, 0, stream,
                       qb, kb, vb, wqb, bqb, wkb, bkb, wvb, bvb, qh, kh, vt);
    hipLaunchKernelGGL(attn_kernel, dim3(BATCH * NHEAD, 16), blk, 0, stream,
                       qh, kh, vt, ctx);
    hipLaunchKernelGGL(oproj_gemm_kernel, dim3(MROWS / 128, DMODEL / 128), blk, 0, stream,
                       ctx, wob, bob, out);
}